// Round 5
// baseline (923.236 us; speedup 1.0000x reference)
//
#include <hip/hip_runtime.h>
#include <hip/hip_bf16.h>

// CausalMLA: B=2, L=2048, D=2048, H=16, HD=128, LD=32. Inputs fp32 or bf16
// (runtime-detected); pipeline bf16/MFMA; output dtype follows input.
// R5: flash 128-key chunking (cross-lane softmax cost /4); out-GEMM retiled
//     64x128 (1024 blocks, ~8/CU) to hide barrier drain at low occupancy.

#define Bsz 2
#define Lseq 2048
#define Dmod 2048
#define Hn 16
#define HDim 128
#define LDim 32

typedef __bf16 bf16x8 __attribute__((ext_vector_type(8)));
typedef float f32x4 __attribute__((ext_vector_type(4)));
typedef __hip_bfloat16 bf16;

#define GLDS16(g, l)                                                    \
  __builtin_amdgcn_global_load_lds(                                     \
      (const __attribute__((address_space(1))) unsigned int*)(g),       \
      (__attribute__((address_space(3))) unsigned int*)(l), 16, 0, 0)

// ---- small-constants area layout (bf16 element offsets inside `small`) ----
#define SM_COS 0
#define SM_SIN 131072
#define SM_WC 262144     // Wqc|Wkc|Wvc 3*4096 (staging only)
#define SM_BC 274432     // bqc|bkc|bvc 3*32
#define SM_WD 274528     // 4096 (staging only)
#define SM_BD 278624     // 128
#define SM_BO 278752     // 2048
#define SM_BQKV 280800   // bq|bk|bv 3*2048
#define SM_TOT 286944

// ---------------- dtype detector ----------------
__global__ void detect_dtype(const ushort* __restrict__ x, int* __restrict__ flag) {
  int t = threadIdx.x;  // 64 threads
  int bad = 0;
  for (int k = 0; k < 4; ++k) {
    ushort u = x[t * 4 + k];
    int ex = (u >> 7) & 0xFF;
    if (ex >= 0xC0) bad = 1;
  }
  unsigned long long b = __ballot(bad);
  if (t == 0) *flag = (b != 0ULL) ? 1 : 0;  // 1 = inputs are fp32
}

__device__ inline void conv8(const void* src, size_t so, bf16* dst, size_t dof, int f32) {
  if (f32) {
    const float* s = (const float*)src + so;
    bf16 tmp[8] __attribute__((aligned(16)));
    for (int j = 0; j < 8; ++j) tmp[j] = __float2bfloat16(s[j]);
    *(uint4*)&dst[dof] = *(uint4*)tmp;
  } else {
    *(uint4*)&dst[dof] = *(const uint4*)((const ushort*)src + so);
  }
}

__device__ inline float cv1(const void* s, size_t i, int f32) {
  return f32 ? ((const float*)s)[i] : __bfloat162float(((const bf16*)s)[i]);
}

__global__ __launch_bounds__(256) void conv_x(const void* __restrict__ xs,
                                              bf16* __restrict__ xd,
                                              const int* __restrict__ flagp) {
  int f32 = *flagp;
  size_t e = ((size_t)blockIdx.x * 256 + threadIdx.x) * 8;  // grid 4096
  conv8(xs, e, xd, e, f32);
}

// ---------------- prep: small-area conversion + wctG/wdtG ----------------
__global__ __launch_bounds__(256) void prep(
    const void* cosS, const void* sinS, const void* WqcS, const void* WkcS,
    const void* WvcS, const void* bqcS, const void* bkcS, const void* bvcS,
    const void* WdS, const void* bdS, const void* boS, const void* bqS,
    const void* bkS, const void* bvS, bf16* __restrict__ dst,
    bf16* __restrict__ wctG, bf16* __restrict__ wdtG,
    const int* __restrict__ flagp) {
  int f32 = *flagp;
  int tid = blockIdx.x * 256 + threadIdx.x;  // grid 160 -> 40960
  if (tid < SM_TOT / 8) {
    size_t e = (size_t)tid * 8;
    const void* src;
    size_t so;
    if (e < SM_SIN) { src = cosS; so = e - SM_COS; }
    else if (e < SM_WC) { src = sinS; so = e - SM_SIN; }
    else if (e < SM_BC) { size_t r = e - SM_WC; src = (r < 4096) ? WqcS : (r < 8192) ? WkcS : WvcS; so = r & 4095; }
    else if (e < SM_WD) { size_t r = e - SM_BC; src = (r < 32) ? bqcS : (r < 64) ? bkcS : bvcS; so = r & 31; }
    else if (e < SM_BD) { src = WdS; so = e - SM_WD; }
    else if (e < SM_BO) { src = bdS; so = e - SM_BD; }
    else if (e < SM_BQKV) { src = boS; so = e - SM_BO; }
    else { size_t r = e - SM_BQKV; src = (r < 2048) ? bqS : (r < 4096) ? bkS : bvS; so = r & 2047; }
    conv8(src, so, dst, e, f32);
  } else {
    int idx = tid - SM_TOT / 8;
    for (int i = idx; i < 16384; i += 40960 - SM_TOT / 8) {
      if (i < 12288) {
        int reg = i >> 12, rem = i & 4095, n = rem >> 7, k = rem & 127;
        const void* src = (reg == 0) ? WqcS : (reg == 1) ? WkcS : WvcS;
        wctG[i] = __float2bfloat16(cv1(src, (size_t)k * 32 + n, f32));
      } else {
        int i2 = i - 12288, o = i2 >> 5, e = i2 & 31;
        wdtG[i2] = __float2bfloat16(cv1(WdS, (size_t)e * 128 + o, f32));
      }
    }
  }
}

// ---------------- 4 weight transposes: Wt[n][k] = W[k][n] ----------------
__global__ __launch_bounds__(256) void transpose4(const void* __restrict__ WqS,
                                                  const void* __restrict__ WkS,
                                                  const void* __restrict__ WvS,
                                                  const void* __restrict__ WoS,
                                                  bf16* __restrict__ WtQKV,
                                                  bf16* __restrict__ WtO,
                                                  const int* __restrict__ flagp) {
  __shared__ float tile[64][65];
  int f32 = *flagp;
  int z = blockIdx.z;
  const void* W = (z == 0) ? WqS : (z == 1) ? WkS : (z == 2) ? WvS : WoS;
  bf16* Wt = (z == 3) ? WtO : (WtQKV + (size_t)z * 2048 * 2048);
  int n0 = blockIdx.x * 64, k0 = blockIdx.y * 64;
  int t = threadIdx.x;
  int x = (t & 7) * 8, y = t >> 3;
  for (int p = 0; p < 2; ++p) {
    int r = y + p * 32;
    if (f32) {
      const float* src = (const float*)W + (size_t)(k0 + r) * 2048 + n0 + x;
      float4 a = *(const float4*)src;
      float4 b2 = *(const float4*)(src + 4);
      tile[r][x + 0] = a.x; tile[r][x + 1] = a.y; tile[r][x + 2] = a.z; tile[r][x + 3] = a.w;
      tile[r][x + 4] = b2.x; tile[r][x + 5] = b2.y; tile[r][x + 6] = b2.z; tile[r][x + 7] = b2.w;
    } else {
      const ushort* src = (const ushort*)W + (size_t)(k0 + r) * 2048 + n0 + x;
      uint4 u = *(const uint4*)src;
      bf16* e = (bf16*)&u;
      for (int j = 0; j < 8; ++j) tile[r][x + j] = __bfloat162float(e[j]);
    }
  }
  __syncthreads();
  for (int p = 0; p < 2; ++p) {
    int n = y + p * 32;
    bf16 tmp[8] __attribute__((aligned(16)));
    for (int j = 0; j < 8; ++j) tmp[j] = __float2bfloat16(tile[x + j][n]);
    *(uint4*)&Wt[(size_t)(n0 + n) * 2048 + k0 + x] = *(uint4*)tmp;
  }
}

// ---------------- QKV GEMM + fused RoPE + compression (unchanged from R4) ----------------
#define ESTR 136
__global__ __launch_bounds__(256) void gemm_qkv_compress(
    const bf16* __restrict__ A, const bf16* __restrict__ Bt,
    const bf16* __restrict__ small, const bf16* __restrict__ wctG,
    bf16* __restrict__ qc, bf16* __restrict__ kc, bf16* __restrict__ vcT) {
  __shared__ bf16 sh[128 * ESTR];  // 34816 B; first 16KB doubles as lA|lB
  bf16* lA = sh;
  bf16* lB = sh + 4096;
  const int K = 2048;
  int bm = blockIdx.y, bn = blockIdx.x;
  int reg = bn >> 4, h = bn & 15;
  int t = threadIdx.x;
  int lane = t & 63, w = t >> 6;
  int wm = (w >> 1) * 64, wn = (w & 1) * 64;
  int qd = lane >> 4, ln = lane & 15;

  f32x4 acc[4][4] = {};
  const bf16* Ab = A + (size_t)(bm * 128) * K;
  const bf16* Bb = Bt + (size_t)(bn * 128) * K;

  for (int kt = 0; kt < K; kt += 32) {
    for (int p = 0; p < 2; ++p) {
      int slot = t + p * 256;
      int r = slot >> 2, c = (slot & 3) * 8;
      GLDS16(&Ab[(size_t)r * K + kt + c], &lA[slot * 8]);
      GLDS16(&Bb[(size_t)r * K + kt + c], &lB[slot * 8]);
    }
    __syncthreads();
    bf16x8 af[4], bfr[4];
    for (int i = 0; i < 4; ++i) af[i] = *(bf16x8*)&lA[(wm + i * 16 + ln) * 32 + qd * 8];
    for (int j = 0; j < 4; ++j) bfr[j] = *(bf16x8*)&lB[(wn + j * 16 + ln) * 32 + qd * 8];
    for (int i = 0; i < 4; ++i)
      for (int j = 0; j < 4; ++j)
        acc[i][j] = __builtin_amdgcn_mfma_f32_16x16x32_bf16(af[i], bfr[j], acc[i][j], 0, 0, 0);
    __syncthreads();
  }

  for (int j = 0; j < 4; ++j) {
    int col = wn + j * 16 + ln;
    float bv = __bfloat162float(small[SM_BQKV + bn * 128 + col]);
    for (int i = 0; i < 4; ++i)
      for (int r = 0; r < 4; ++r)
        sh[(wm + i * 16 + qd * 4 + r) * ESTR + col] = __float2bfloat16(acc[i][j][r] + bv);
  }
  __syncthreads();

  int r0 = w * 32;
  int b = bm >> 4;
  int bh = b * Hn + h;
  bf16x8 bfr2[2][4];
  for (int nt = 0; nt < 2; ++nt)
    for (int kt = 0; kt < 4; ++kt)
      bfr2[nt][kt] = *(const bf16x8*)&wctG[reg * 4096 + (nt * 16 + ln) * 128 + kt * 32 + qd * 8];
  float bc[2];
  bc[0] = __bfloat162float(small[SM_BC + reg * 32 + ln]);
  bc[1] = __bfloat162float(small[SM_BC + reg * 32 + 16 + ln]);

  for (int mt = 0; mt < 2; ++mt) {
    int lb = r0 + mt * 16 + ln;
    int lg = (bm & 15) * 128 + lb;
    f32x4 c2[2] = {};
    for (int kt = 0; kt < 4; ++kt) {
      uint4 u = *(uint4*)&sh[lb * ESTR + kt * 32 + qd * 8];
      if (reg < 2) {
        bf16* e8 = (bf16*)&u;
        int pbase = kt * 16 + qd * 4;
        for (int j = 0; j < 4; ++j) {
          float cvv = __bfloat162float(small[SM_COS + (size_t)lg * 64 + pbase + j]);
          float svv = __bfloat162float(small[SM_SIN + (size_t)lg * 64 + pbase + j]);
          float ev = __bfloat162float(e8[2 * j]);
          float ov = __bfloat162float(e8[2 * j + 1]);
          e8[2 * j] = __float2bfloat16(ev * cvv - ov * svv);
          e8[2 * j + 1] = __float2bfloat16(ev * svv + ov * cvv);
        }
      }
      bf16x8 a = *(bf16x8*)&u;
      c2[0] = __builtin_amdgcn_mfma_f32_16x16x32_bf16(a, bfr2[0][kt], c2[0], 0, 0, 0);
      c2[1] = __builtin_amdgcn_mfma_f32_16x16x32_bf16(a, bfr2[1][kt], c2[1], 0, 0, 0);
    }
    int lgbase = (bm & 15) * 128 + r0 + mt * 16 + qd * 4;
    if (reg < 2) {
      bf16* dst = (reg == 0) ? qc : kc;
      for (int nt = 0; nt < 2; ++nt)
        for (int r = 0; r < 4; ++r)
          dst[((size_t)bh * Lseq + lgbase + r) * 32 + nt * 16 + ln] =
              __float2bfloat16(c2[nt][r] + bc[nt]);
    } else {
      for (int nt = 0; nt < 2; ++nt) {
        bf16 p4[4] __attribute__((aligned(8)));
        for (int r = 0; r < 4; ++r) p4[r] = __float2bfloat16(c2[nt][r] + bc[nt]);
        *(uint2*)&vcT[((size_t)bh * 32 + nt * 16 + ln) * Lseq + lgbase] = *(uint2*)p4;
      }
    }
  }
}

// ---------------- output GEMM: 64x128 tiles, 1024 blocks (~8/CU) ----------------
__global__ __launch_bounds__(256) void gemm_bias_out(const bf16* __restrict__ A,
                                                     const bf16* __restrict__ Bt,
                                                     const bf16* __restrict__ bias,
                                                     void* __restrict__ C,
                                                     int M, int N, int K,
                                                     const int* __restrict__ flagp) {
  __shared__ bf16 lA[64 * 32];
  __shared__ bf16 lB[128 * 32];
  int f32out = *flagp;
  int bm = blockIdx.y, bn = blockIdx.x;  // bm 0..63 (64 rows), bn 0..15 (128 cols)
  int t = threadIdx.x;
  int lane = t & 63, w = t >> 6;
  int wm = (w >> 1) * 32, wn = (w & 1) * 64;
  int qd = lane >> 4, ln = lane & 15;

  f32x4 acc[2][4] = {};
  const bf16* Ab = A + (size_t)(bm * 64) * K;
  const bf16* Bb = Bt + (size_t)(bn * 128) * K;

  for (int kt = 0; kt < K; kt += 32) {
    {
      int r = t >> 2, c = (t & 3) * 8;
      GLDS16(&Ab[(size_t)r * K + kt + c], &lA[t * 8]);
    }
    for (int p = 0; p < 2; ++p) {
      int slot = t + p * 256;
      int r = slot >> 2, c = (slot & 3) * 8;
      GLDS16(&Bb[(size_t)r * K + kt + c], &lB[slot * 8]);
    }
    __syncthreads();
    bf16x8 af[2], bfr[4];
    for (int i = 0; i < 2; ++i) af[i] = *(bf16x8*)&lA[(wm + i * 16 + ln) * 32 + qd * 8];
    for (int j = 0; j < 4; ++j) bfr[j] = *(bf16x8*)&lB[(wn + j * 16 + ln) * 32 + qd * 8];
    for (int i = 0; i < 2; ++i)
      for (int j = 0; j < 4; ++j)
        acc[i][j] = __builtin_amdgcn_mfma_f32_16x16x32_bf16(af[i], bfr[j], acc[i][j], 0, 0, 0);
    __syncthreads();
  }
  for (int i = 0; i < 2; ++i)
    for (int j = 0; j < 4; ++j) {
      int col = bn * 128 + wn + j * 16 + ln;
      float bv = __bfloat162float(bias[col]);
      for (int r = 0; r < 4; ++r) {
        int row = bm * 64 + wm + i * 16 + qd * 4 + r;
        float v = acc[i][j][r] + bv;
        if (f32out) ((float*)C)[(size_t)row * N + col] = v;
        else ((bf16*)C)[(size_t)row * N + col] = __float2bfloat16(v);
      }
    }
}

// ---------------- flash attention: 128-key chunks + fused decompress ----------------
__global__ __launch_bounds__(256) void flash32(const bf16* __restrict__ qc,
                                               const bf16* __restrict__ kc,
                                               const bf16* __restrict__ vcT,
                                               const bf16* __restrict__ small,
                                               const bf16* __restrict__ wdtG,
                                               bf16* __restrict__ y) {
  __shared__ bf16 pbuf[4][16 * 136];  // 16 q-rows x 128 P-cols (+8 pad)
  int t = threadIdx.x;
  int lane = t & 63, w = t >> 6;
  int qd = lane >> 4, ln = lane & 15;
  int blk = blockIdx.x;
  int lt = blk & 31;
  int bh = blk >> 5, h = bh & 15, b = bh >> 4;
  int q0 = lt * 64 + w * 16;

  bf16x8 qf = *(const bf16x8*)&qc[((size_t)bh * Lseq + q0 + ln) * 32 + qd * 8];

  f32x4 o0 = {}, o1 = {};
  float m[4], lsum[4];
  for (int r = 0; r < 4; ++r) { m[r] = -1e30f; lsum[r] = 0.f; }
  const float scale = 0.17677669529663687f;  // 1/sqrt(32)
  bf16* pb = pbuf[w];
  const bf16* kbase = kc + (size_t)bh * Lseq * 32;
  const bf16* vbase = vcT + (size_t)bh * 32 * Lseq;
  int kmax = q0 + 16;
  int nc = (kmax + 127) >> 7;

  for (int ch = 0; ch < nc; ++ch) {
    int k0 = ch << 7;
    int rem = kmax - k0;  // > 0
    int jmax = (rem >= 128) ? 4 : ((rem + 31) >> 5);
    int cmax = jmax * 2;
    f32x4 s[8];
    for (int c = 0; c < 8; ++c)
      if (c < cmax) {
        bf16x8 kf = *(const bf16x8*)&kbase[(size_t)(k0 + c * 16 + ln) * 32 + qd * 8];
        f32x4 z = {};
        s[c] = __builtin_amdgcn_mfma_f32_16x16x32_bf16(qf, kf, z, 0, 0, 0);
      }
    for (int r = 0; r < 4; ++r) {
      int qrow = q0 + qd * 4 + r;
      float mx = -1e30f;
      for (int c = 0; c < 8; ++c)
        if (c < cmax) {
          s[c][r] = (k0 + c * 16 + ln <= qrow) ? s[c][r] * scale : -1e30f;
          mx = fmaxf(mx, s[c][r]);
        }
      for (int off = 1; off < 16; off <<= 1) mx = fmaxf(mx, __shfl_xor(mx, off, 64));
      float mn = fmaxf(m[r], mx);
      float alpha = __expf(m[r] - mn);
      m[r] = mn;
      float rs = 0.f;
      for (int c = 0; c < 8; ++c)
        if (c < cmax) {
          float e = __expf(s[c][r] - mn);
          s[c][r] = e;
          rs += e;
        }
      for (int off = 1; off < 16; off <<= 1) rs += __shfl_xor(rs, off, 64);
      lsum[r] = lsum[r] * alpha + rs;
      o0[r] *= alpha;
      o1[r] *= alpha;
      for (int c = 0; c < 8; ++c)
        if (c < cmax)
          pb[(qd * 4 + r) * 136 + c * 16 + ln] = __float2bfloat16(s[c][r]);
    }
    asm volatile("s_waitcnt lgkmcnt(0)" ::: "memory");  // wave-local LDS W->R order
    for (int j = 0; j < 4; ++j)
      if (j < jmax) {
        bf16x8 pf = *(bf16x8*)&pb[ln * 136 + j * 32 + qd * 8];
        bf16x8 vf0 = *(const bf16x8*)&vbase[(size_t)ln * Lseq + k0 + j * 32 + qd * 8];
        bf16x8 vf1 = *(const bf16x8*)&vbase[(size_t)(16 + ln) * Lseq + k0 + j * 32 + qd * 8];
        o0 = __builtin_amdgcn_mfma_f32_16x16x32_bf16(pf, vf0, o0, 0, 0, 0);
        o1 = __builtin_amdgcn_mfma_f32_16x16x32_bf16(pf, vf1, o1, 0, 0, 0);
      }
  }
  // epilogue: normalize, C->A layout via LDS, x WdT -> y
  for (int r = 0; r < 4; ++r) {
    float inv = 1.0f / lsum[r];
    pb[(qd * 4 + r) * 136 + ln] = __float2bfloat16(o0[r] * inv);
    pb[(qd * 4 + r) * 136 + 16 + ln] = __float2bfloat16(o1[r] * inv);
  }
  asm volatile("s_waitcnt lgkmcnt(0)" ::: "memory");
  bf16x8 pf = *(bf16x8*)&pb[ln * 136 + qd * 8];
  for (int nt = 0; nt < 8; ++nt) {
    bf16x8 bfr = *(const bf16x8*)&wdtG[(nt * 16 + ln) * 32 + qd * 8];
    f32x4 yacc = {};
    yacc = __builtin_amdgcn_mfma_f32_16x16x32_bf16(pf, bfr, yacc, 0, 0, 0);
    float bb = __bfloat162float(small[SM_BD + nt * 16 + ln]);
    for (int rr = 0; rr < 4; ++rr) {
      int l = q0 + qd * 4 + rr;
      y[(size_t)(b * Lseq + l) * Dmod + h * 128 + nt * 16 + ln] =
          __float2bfloat16(yacc[rr] + bb);
    }
  }
}

extern "C" void kernel_launch(void* const* d_in, const int* in_sizes, int n_in,
                              void* d_out, int out_size, void* d_ws, size_t ws_size,
                              hipStream_t stream) {
  const void* x = d_in[0];
  const void* cosS = d_in[1];
  const void* sinS = d_in[2];
  const void* Wq = d_in[3];
  const void* bq = d_in[4];
  const void* Wk = d_in[5];
  const void* bk = d_in[6];
  const void* Wv = d_in[7];
  const void* bv = d_in[8];
  const void* Wqc = d_in[9];
  const void* bqc = d_in[10];
  const void* Wkc = d_in[11];
  const void* bkc = d_in[12];
  const void* Wvc = d_in[13];
  const void* bvc = d_in[14];
  const void* Wd = d_in[15];
  const void* bd = d_in[16];
  const void* Wo = d_in[17];
  const void* bo = d_in[18];

  char* ws = (char*)d_ws;
  size_t off = 0;
  auto alloc = [&](size_t bytes) {
    char* p = ws + off;
    off += (bytes + 255) & ~(size_t)255;
    return p;
  };
  int* flag = (int*)alloc(256);
  bf16* small = (bf16*)alloc((size_t)SM_TOT * 2);
  bf16* wctG = (bf16*)alloc((size_t)12288 * 2);
  bf16* wdtG = (bf16*)alloc((size_t)4096 * 2);
  bf16* xb = (bf16*)alloc((size_t)4096 * 2048 * 2);
  bf16* WtQKV = (bf16*)alloc((size_t)6144 * 2048 * 2);
  bf16* WtO = (bf16*)alloc((size_t)2048 * 2048 * 2);
  bf16* qcW = (bf16*)alloc((size_t)65536 * 32 * 2);
  bf16* kcW = (bf16*)alloc((size_t)65536 * 32 * 2);
  bf16* vcTW = (bf16*)alloc((size_t)65536 * 32 * 2);
  bf16* yW = (bf16*)alloc((size_t)4096 * 2048 * 2);

  dim3 tb(256);
  detect_dtype<<<1, 64, 0, stream>>>((const ushort*)x, flag);
  prep<<<160, tb, 0, stream>>>(cosS, sinS, Wqc, Wkc, Wvc, bqc, bkc, bvc, Wd, bd, bo, bq,
                               bk, bv, small, wctG, wdtG, flag);
  transpose4<<<dim3(32, 32, 4), tb, 0, stream>>>(Wq, Wk, Wv, Wo, WtQKV, WtO, flag);
  conv_x<<<4096, tb, 0, stream>>>(x, xb, flag);
  gemm_qkv_compress<<<dim3(48, 32), tb, 0, stream>>>(xb, WtQKV, small, wctG, qcW, kcW,
                                                     vcTW);
  flash32<<<1024, tb, 0, stream>>>(qcW, kcW, vcTW, small, wdtG, yW);
  gemm_bias_out<<<dim3(16, 64), tb, 0, stream>>>(yW, WtO, small + SM_BO, d_out, 4096, 2048,
                                                 2048, flag);
}

// Round 6
// 492.474 us; speedup vs baseline: 1.8747x; 1.8747x over previous
//
#include <hip/hip_runtime.h>
#include <hip/hip_bf16.h>

// CausalMLA: B=2, L=2048, D=2048, H=16, HD=128, LD=32. Inputs fp32 or bf16
// (runtime-detected); pipeline bf16/MFMA; output dtype follows input.
// R6: flash chunks fully static (no runtime guards -> no scratch demotion of
//     s[]); causal big-tiles-first block order. Rest unchanged from R5.

#define Bsz 2
#define Lseq 2048
#define Dmod 2048
#define Hn 16
#define HDim 128
#define LDim 32

typedef __bf16 bf16x8 __attribute__((ext_vector_type(8)));
typedef float f32x4 __attribute__((ext_vector_type(4)));
typedef __hip_bfloat16 bf16;

#define GLDS16(g, l)                                                    \
  __builtin_amdgcn_global_load_lds(                                     \
      (const __attribute__((address_space(1))) unsigned int*)(g),       \
      (__attribute__((address_space(3))) unsigned int*)(l), 16, 0, 0)

// ---- small-constants area layout (bf16 element offsets inside `small`) ----
#define SM_COS 0
#define SM_SIN 131072
#define SM_WC 262144     // Wqc|Wkc|Wvc 3*4096 (staging only)
#define SM_BC 274432     // bqc|bkc|bvc 3*32
#define SM_WD 274528     // 4096 (staging only)
#define SM_BD 278624     // 128
#define SM_BO 278752     // 2048
#define SM_BQKV 280800   // bq|bk|bv 3*2048
#define SM_TOT 286944

// ---------------- dtype detector ----------------
__global__ void detect_dtype(const ushort* __restrict__ x, int* __restrict__ flag) {
  int t = threadIdx.x;  // 64 threads
  int bad = 0;
  for (int k = 0; k < 4; ++k) {
    ushort u = x[t * 4 + k];
    int ex = (u >> 7) & 0xFF;
    if (ex >= 0xC0) bad = 1;
  }
  unsigned long long b = __ballot(bad);
  if (t == 0) *flag = (b != 0ULL) ? 1 : 0;  // 1 = inputs are fp32
}

__device__ inline void conv8(const void* src, size_t so, bf16* dst, size_t dof, int f32) {
  if (f32) {
    const float* s = (const float*)src + so;
    bf16 tmp[8] __attribute__((aligned(16)));
    for (int j = 0; j < 8; ++j) tmp[j] = __float2bfloat16(s[j]);
    *(uint4*)&dst[dof] = *(uint4*)tmp;
  } else {
    *(uint4*)&dst[dof] = *(const uint4*)((const ushort*)src + so);
  }
}

__device__ inline float cv1(const void* s, size_t i, int f32) {
  return f32 ? ((const float*)s)[i] : __bfloat162float(((const bf16*)s)[i]);
}

__global__ __launch_bounds__(256) void conv_x(const void* __restrict__ xs,
                                              bf16* __restrict__ xd,
                                              const int* __restrict__ flagp) {
  int f32 = *flagp;
  size_t e = ((size_t)blockIdx.x * 256 + threadIdx.x) * 8;  // grid 4096
  conv8(xs, e, xd, e, f32);
}

// ---------------- prep: small-area conversion + wctG/wdtG ----------------
__global__ __launch_bounds__(256) void prep(
    const void* cosS, const void* sinS, const void* WqcS, const void* WkcS,
    const void* WvcS, const void* bqcS, const void* bkcS, const void* bvcS,
    const void* WdS, const void* bdS, const void* boS, const void* bqS,
    const void* bkS, const void* bvS, bf16* __restrict__ dst,
    bf16* __restrict__ wctG, bf16* __restrict__ wdtG,
    const int* __restrict__ flagp) {
  int f32 = *flagp;
  int tid = blockIdx.x * 256 + threadIdx.x;  // grid 160 -> 40960
  if (tid < SM_TOT / 8) {
    size_t e = (size_t)tid * 8;
    const void* src;
    size_t so;
    if (e < SM_SIN) { src = cosS; so = e - SM_COS; }
    else if (e < SM_WC) { src = sinS; so = e - SM_SIN; }
    else if (e < SM_BC) { size_t r = e - SM_WC; src = (r < 4096) ? WqcS : (r < 8192) ? WkcS : WvcS; so = r & 4095; }
    else if (e < SM_WD) { size_t r = e - SM_BC; src = (r < 32) ? bqcS : (r < 64) ? bkcS : bvcS; so = r & 31; }
    else if (e < SM_BD) { src = WdS; so = e - SM_WD; }
    else if (e < SM_BO) { src = bdS; so = e - SM_BD; }
    else if (e < SM_BQKV) { src = boS; so = e - SM_BO; }
    else { size_t r = e - SM_BQKV; src = (r < 2048) ? bqS : (r < 4096) ? bkS : bvS; so = r & 2047; }
    conv8(src, so, dst, e, f32);
  } else {
    int idx = tid - SM_TOT / 8;
    for (int i = idx; i < 16384; i += 40960 - SM_TOT / 8) {
      if (i < 12288) {
        int reg = i >> 12, rem = i & 4095, n = rem >> 7, k = rem & 127;
        const void* src = (reg == 0) ? WqcS : (reg == 1) ? WkcS : WvcS;
        wctG[i] = __float2bfloat16(cv1(src, (size_t)k * 32 + n, f32));
      } else {
        int i2 = i - 12288, o = i2 >> 5, e = i2 & 31;
        wdtG[i2] = __float2bfloat16(cv1(WdS, (size_t)e * 128 + o, f32));
      }
    }
  }
}

// ---------------- 4 weight transposes: Wt[n][k] = W[k][n] ----------------
__global__ __launch_bounds__(256) void transpose4(const void* __restrict__ WqS,
                                                  const void* __restrict__ WkS,
                                                  const void* __restrict__ WvS,
                                                  const void* __restrict__ WoS,
                                                  bf16* __restrict__ WtQKV,
                                                  bf16* __restrict__ WtO,
                                                  const int* __restrict__ flagp) {
  __shared__ float tile[64][65];
  int f32 = *flagp;
  int z = blockIdx.z;
  const void* W = (z == 0) ? WqS : (z == 1) ? WkS : (z == 2) ? WvS : WoS;
  bf16* Wt = (z == 3) ? WtO : (WtQKV + (size_t)z * 2048 * 2048);
  int n0 = blockIdx.x * 64, k0 = blockIdx.y * 64;
  int t = threadIdx.x;
  int x = (t & 7) * 8, y = t >> 3;
  for (int p = 0; p < 2; ++p) {
    int r = y + p * 32;
    if (f32) {
      const float* src = (const float*)W + (size_t)(k0 + r) * 2048 + n0 + x;
      float4 a = *(const float4*)src;
      float4 b2 = *(const float4*)(src + 4);
      tile[r][x + 0] = a.x; tile[r][x + 1] = a.y; tile[r][x + 2] = a.z; tile[r][x + 3] = a.w;
      tile[r][x + 4] = b2.x; tile[r][x + 5] = b2.y; tile[r][x + 6] = b2.z; tile[r][x + 7] = b2.w;
    } else {
      const ushort* src = (const ushort*)W + (size_t)(k0 + r) * 2048 + n0 + x;
      uint4 u = *(const uint4*)src;
      bf16* e = (bf16*)&u;
      for (int j = 0; j < 8; ++j) tile[r][x + j] = __bfloat162float(e[j]);
    }
  }
  __syncthreads();
  for (int p = 0; p < 2; ++p) {
    int n = y + p * 32;
    bf16 tmp[8] __attribute__((aligned(16)));
    for (int j = 0; j < 8; ++j) tmp[j] = __float2bfloat16(tile[x + j][n]);
    *(uint4*)&Wt[(size_t)(n0 + n) * 2048 + k0 + x] = *(uint4*)tmp;
  }
}

// ---------------- QKV GEMM + fused RoPE + compression ----------------
#define ESTR 136
__global__ __launch_bounds__(256) void gemm_qkv_compress(
    const bf16* __restrict__ A, const bf16* __restrict__ Bt,
    const bf16* __restrict__ small, const bf16* __restrict__ wctG,
    bf16* __restrict__ qc, bf16* __restrict__ kc, bf16* __restrict__ vcT) {
  __shared__ bf16 sh[128 * ESTR];  // 34816 B; first 16KB doubles as lA|lB
  bf16* lA = sh;
  bf16* lB = sh + 4096;
  const int K = 2048;
  int bm = blockIdx.y, bn = blockIdx.x;
  int reg = bn >> 4, h = bn & 15;
  int t = threadIdx.x;
  int lane = t & 63, w = t >> 6;
  int wm = (w >> 1) * 64, wn = (w & 1) * 64;
  int qd = lane >> 4, ln = lane & 15;

  f32x4 acc[4][4] = {};
  const bf16* Ab = A + (size_t)(bm * 128) * K;
  const bf16* Bb = Bt + (size_t)(bn * 128) * K;

  for (int kt = 0; kt < K; kt += 32) {
    for (int p = 0; p < 2; ++p) {
      int slot = t + p * 256;
      int r = slot >> 2, c = (slot & 3) * 8;
      GLDS16(&Ab[(size_t)r * K + kt + c], &lA[slot * 8]);
      GLDS16(&Bb[(size_t)r * K + kt + c], &lB[slot * 8]);
    }
    __syncthreads();
    bf16x8 af[4], bfr[4];
    for (int i = 0; i < 4; ++i) af[i] = *(bf16x8*)&lA[(wm + i * 16 + ln) * 32 + qd * 8];
    for (int j = 0; j < 4; ++j) bfr[j] = *(bf16x8*)&lB[(wn + j * 16 + ln) * 32 + qd * 8];
    for (int i = 0; i < 4; ++i)
      for (int j = 0; j < 4; ++j)
        acc[i][j] = __builtin_amdgcn_mfma_f32_16x16x32_bf16(af[i], bfr[j], acc[i][j], 0, 0, 0);
    __syncthreads();
  }

  for (int j = 0; j < 4; ++j) {
    int col = wn + j * 16 + ln;
    float bv = __bfloat162float(small[SM_BQKV + bn * 128 + col]);
    for (int i = 0; i < 4; ++i)
      for (int r = 0; r < 4; ++r)
        sh[(wm + i * 16 + qd * 4 + r) * ESTR + col] = __float2bfloat16(acc[i][j][r] + bv);
  }
  __syncthreads();

  int r0 = w * 32;
  int b = bm >> 4;
  int bh = b * Hn + h;
  bf16x8 bfr2[2][4];
  for (int nt = 0; nt < 2; ++nt)
    for (int kt = 0; kt < 4; ++kt)
      bfr2[nt][kt] = *(const bf16x8*)&wctG[reg * 4096 + (nt * 16 + ln) * 128 + kt * 32 + qd * 8];
  float bc[2];
  bc[0] = __bfloat162float(small[SM_BC + reg * 32 + ln]);
  bc[1] = __bfloat162float(small[SM_BC + reg * 32 + 16 + ln]);

  for (int mt = 0; mt < 2; ++mt) {
    int lb = r0 + mt * 16 + ln;
    int lg = (bm & 15) * 128 + lb;
    f32x4 c2[2] = {};
    for (int kt = 0; kt < 4; ++kt) {
      uint4 u = *(uint4*)&sh[lb * ESTR + kt * 32 + qd * 8];
      if (reg < 2) {
        bf16* e8 = (bf16*)&u;
        int pbase = kt * 16 + qd * 4;
        for (int j = 0; j < 4; ++j) {
          float cvv = __bfloat162float(small[SM_COS + (size_t)lg * 64 + pbase + j]);
          float svv = __bfloat162float(small[SM_SIN + (size_t)lg * 64 + pbase + j]);
          float ev = __bfloat162float(e8[2 * j]);
          float ov = __bfloat162float(e8[2 * j + 1]);
          e8[2 * j] = __float2bfloat16(ev * cvv - ov * svv);
          e8[2 * j + 1] = __float2bfloat16(ev * svv + ov * cvv);
        }
      }
      bf16x8 a = *(bf16x8*)&u;
      c2[0] = __builtin_amdgcn_mfma_f32_16x16x32_bf16(a, bfr2[0][kt], c2[0], 0, 0, 0);
      c2[1] = __builtin_amdgcn_mfma_f32_16x16x32_bf16(a, bfr2[1][kt], c2[1], 0, 0, 0);
    }
    int lgbase = (bm & 15) * 128 + r0 + mt * 16 + qd * 4;
    if (reg < 2) {
      bf16* dst = (reg == 0) ? qc : kc;
      for (int nt = 0; nt < 2; ++nt)
        for (int r = 0; r < 4; ++r)
          dst[((size_t)bh * Lseq + lgbase + r) * 32 + nt * 16 + ln] =
              __float2bfloat16(c2[nt][r] + bc[nt]);
    } else {
      for (int nt = 0; nt < 2; ++nt) {
        bf16 p4[4] __attribute__((aligned(8)));
        for (int r = 0; r < 4; ++r) p4[r] = __float2bfloat16(c2[nt][r] + bc[nt]);
        *(uint2*)&vcT[((size_t)bh * 32 + nt * 16 + ln) * Lseq + lgbase] = *(uint2*)p4;
      }
    }
  }
}

// ---------------- output GEMM: 64x128 tiles, 1024 blocks ----------------
__global__ __launch_bounds__(256) void gemm_bias_out(const bf16* __restrict__ A,
                                                     const bf16* __restrict__ Bt,
                                                     const bf16* __restrict__ bias,
                                                     void* __restrict__ C,
                                                     int M, int N, int K,
                                                     const int* __restrict__ flagp) {
  __shared__ bf16 lA[64 * 32];
  __shared__ bf16 lB[128 * 32];
  int f32out = *flagp;
  int bm = blockIdx.y, bn = blockIdx.x;
  int t = threadIdx.x;
  int lane = t & 63, w = t >> 6;
  int wm = (w >> 1) * 32, wn = (w & 1) * 64;
  int qd = lane >> 4, ln = lane & 15;

  f32x4 acc[2][4] = {};
  const bf16* Ab = A + (size_t)(bm * 64) * K;
  const bf16* Bb = Bt + (size_t)(bn * 128) * K;

  for (int kt = 0; kt < K; kt += 32) {
    {
      int r = t >> 2, c = (t & 3) * 8;
      GLDS16(&Ab[(size_t)r * K + kt + c], &lA[t * 8]);
    }
    for (int p = 0; p < 2; ++p) {
      int slot = t + p * 256;
      int r = slot >> 2, c = (slot & 3) * 8;
      GLDS16(&Bb[(size_t)r * K + kt + c], &lB[slot * 8]);
    }
    __syncthreads();
    bf16x8 af[2], bfr[4];
    for (int i = 0; i < 2; ++i) af[i] = *(bf16x8*)&lA[(wm + i * 16 + ln) * 32 + qd * 8];
    for (int j = 0; j < 4; ++j) bfr[j] = *(bf16x8*)&lB[(wn + j * 16 + ln) * 32 + qd * 8];
    for (int i = 0; i < 2; ++i)
      for (int j = 0; j < 4; ++j)
        acc[i][j] = __builtin_amdgcn_mfma_f32_16x16x32_bf16(af[i], bfr[j], acc[i][j], 0, 0, 0);
    __syncthreads();
  }
  for (int i = 0; i < 2; ++i)
    for (int j = 0; j < 4; ++j) {
      int col = bn * 128 + wn + j * 16 + ln;
      float bv = __bfloat162float(bias[col]);
      for (int r = 0; r < 4; ++r) {
        int row = bm * 64 + wm + i * 16 + qd * 4 + r;
        float v = acc[i][j][r] + bv;
        if (f32out) ((float*)C)[(size_t)row * N + col] = v;
        else ((bf16*)C)[(size_t)row * N + col] = __float2bfloat16(v);
      }
    }
}

// ---------------- flash attention: static 128-key chunks + fused decompress ----------------
// All chunk work is compile-time static (causal mask handles the boundary);
// chunk overrun past kmax reads valid K/V rows (<= L) and masks them to 0.
__global__ __launch_bounds__(256) void flash32(const bf16* __restrict__ qc,
                                               const bf16* __restrict__ kc,
                                               const bf16* __restrict__ vcT,
                                               const bf16* __restrict__ small,
                                               const bf16* __restrict__ wdtG,
                                               bf16* __restrict__ y) {
  __shared__ bf16 pbuf[4][16 * 136];
  int t = threadIdx.x;
  int lane = t & 63, w = t >> 6;
  int qd = lane >> 4, ln = lane & 15;
  int blk = blockIdx.x;
  int lt = 31 - (blk & 31);  // big query tiles dispatch first (causal tail)
  int bh = blk >> 5, h = bh & 15, b = bh >> 4;
  int q0 = lt * 64 + w * 16;

  bf16x8 qf = *(const bf16x8*)&qc[((size_t)bh * Lseq + q0 + ln) * 32 + qd * 8];

  f32x4 o0 = {}, o1 = {};
  float m[4], lsum[4];
  for (int r = 0; r < 4; ++r) { m[r] = -1e30f; lsum[r] = 0.f; }
  const float scale = 0.17677669529663687f;  // 1/sqrt(32)
  bf16* pb = pbuf[w];
  const bf16* kbase = kc + (size_t)bh * Lseq * 32;
  const bf16* vbase = vcT + (size_t)bh * 32 * Lseq;
  int nc = (q0 + 16 + 127) >> 7;  // full 128-key chunks, last one mask-trimmed

  for (int ch = 0; ch < nc; ++ch) {
    int k0 = ch << 7;
    f32x4 s[8];
#pragma unroll
    for (int c = 0; c < 8; ++c) {
      bf16x8 kf = *(const bf16x8*)&kbase[(size_t)(k0 + c * 16 + ln) * 32 + qd * 8];
      f32x4 z = {};
      s[c] = __builtin_amdgcn_mfma_f32_16x16x32_bf16(qf, kf, z, 0, 0, 0);
    }
#pragma unroll
    for (int r = 0; r < 4; ++r) {
      int qrow = q0 + qd * 4 + r;
      float mx = -1e30f;
#pragma unroll
      for (int c = 0; c < 8; ++c) {
        float v = (k0 + c * 16 + ln <= qrow) ? s[c][r] * scale : -1e30f;
        s[c][r] = v;
        mx = fmaxf(mx, v);
      }
      for (int off = 1; off < 16; off <<= 1) mx = fmaxf(mx, __shfl_xor(mx, off, 64));
      float mn = fmaxf(m[r], mx);
      float alpha = __expf(m[r] - mn);
      m[r] = mn;
      float rs = 0.f;
#pragma unroll
      for (int c = 0; c < 8; ++c) {
        float e = __expf(s[c][r] - mn);
        s[c][r] = e;
        rs += e;
      }
      for (int off = 1; off < 16; off <<= 1) rs += __shfl_xor(rs, off, 64);
      lsum[r] = lsum[r] * alpha + rs;
      o0[r] *= alpha;
      o1[r] *= alpha;
#pragma unroll
      for (int c = 0; c < 8; ++c)
        pb[(qd * 4 + r) * 136 + c * 16 + ln] = __float2bfloat16(s[c][r]);
    }
    asm volatile("s_waitcnt lgkmcnt(0)" ::: "memory");  // wave-local LDS W->R order
#pragma unroll
    for (int j = 0; j < 4; ++j) {
      bf16x8 pf = *(bf16x8*)&pb[ln * 136 + j * 32 + qd * 8];
      bf16x8 vf0 = *(const bf16x8*)&vbase[(size_t)ln * Lseq + k0 + j * 32 + qd * 8];
      bf16x8 vf1 = *(const bf16x8*)&vbase[(size_t)(16 + ln) * Lseq + k0 + j * 32 + qd * 8];
      o0 = __builtin_amdgcn_mfma_f32_16x16x32_bf16(pf, vf0, o0, 0, 0, 0);
      o1 = __builtin_amdgcn_mfma_f32_16x16x32_bf16(pf, vf1, o1, 0, 0, 0);
    }
  }
  // epilogue: normalize, C->A layout via LDS, x WdT -> y
#pragma unroll
  for (int r = 0; r < 4; ++r) {
    float inv = 1.0f / lsum[r];
    pb[(qd * 4 + r) * 136 + ln] = __float2bfloat16(o0[r] * inv);
    pb[(qd * 4 + r) * 136 + 16 + ln] = __float2bfloat16(o1[r] * inv);
  }
  asm volatile("s_waitcnt lgkmcnt(0)" ::: "memory");
  bf16x8 pf = *(bf16x8*)&pb[ln * 136 + qd * 8];
#pragma unroll
  for (int nt = 0; nt < 8; ++nt) {
    bf16x8 bfr = *(const bf16x8*)&wdtG[(nt * 16 + ln) * 32 + qd * 8];
    f32x4 yacc = {};
    yacc = __builtin_amdgcn_mfma_f32_16x16x32_bf16(pf, bfr, yacc, 0, 0, 0);
    float bb = __bfloat162float(small[SM_BD + nt * 16 + ln]);
    for (int rr = 0; rr < 4; ++rr) {
      int l = q0 + qd * 4 + rr;
      y[(size_t)(b * Lseq + l) * Dmod + h * 128 + nt * 16 + ln] =
          __float2bfloat16(yacc[rr] + bb);
    }
  }
}

extern "C" void kernel_launch(void* const* d_in, const int* in_sizes, int n_in,
                              void* d_out, int out_size, void* d_ws, size_t ws_size,
                              hipStream_t stream) {
  const void* x = d_in[0];
  const void* cosS = d_in[1];
  const void* sinS = d_in[2];
  const void* Wq = d_in[3];
  const void* bq = d_in[4];
  const void* Wk = d_in[5];
  const void* bk = d_in[6];
  const void* Wv = d_in[7];
  const void* bv = d_in[8];
  const void* Wqc = d_in[9];
  const void* bqc = d_in[10];
  const void* Wkc = d_in[11];
  const void* bkc = d_in[12];
  const void* Wvc = d_in[13];
  const void* bvc = d_in[14];
  const void* Wd = d_in[15];
  const void* bd = d_in[16];
  const void* Wo = d_in[17];
  const void* bo = d_in[18];

  char* ws = (char*)d_ws;
  size_t off = 0;
  auto alloc = [&](size_t bytes) {
    char* p = ws + off;
    off += (bytes + 255) & ~(size_t)255;
    return p;
  };
  int* flag = (int*)alloc(256);
  bf16* small = (bf16*)alloc((size_t)SM_TOT * 2);
  bf16* wctG = (bf16*)alloc((size_t)12288 * 2);
  bf16* wdtG = (bf16*)alloc((size_t)4096 * 2);
  bf16* xb = (bf16*)alloc((size_t)4096 * 2048 * 2);
  bf16* WtQKV = (bf16*)alloc((size_t)6144 * 2048 * 2);
  bf16* WtO = (bf16*)alloc((size_t)2048 * 2048 * 2);
  bf16* qcW = (bf16*)alloc((size_t)65536 * 32 * 2);
  bf16* kcW = (bf16*)alloc((size_t)65536 * 32 * 2);
  bf16* vcTW = (bf16*)alloc((size_t)65536 * 32 * 2);
  bf16* yW = (bf16*)alloc((size_t)4096 * 2048 * 2);

  dim3 tb(256);
  detect_dtype<<<1, 64, 0, stream>>>((const ushort*)x, flag);
  prep<<<160, tb, 0, stream>>>(cosS, sinS, Wqc, Wkc, Wvc, bqc, bkc, bvc, Wd, bd, bo, bq,
                               bk, bv, small, wctG, wdtG, flag);
  transpose4<<<dim3(32, 32, 4), tb, 0, stream>>>(Wq, Wk, Wv, Wo, WtQKV, WtO, flag);
  conv_x<<<4096, tb, 0, stream>>>(x, xb, flag);
  gemm_qkv_compress<<<dim3(48, 32), tb, 0, stream>>>(xb, WtQKV, small, wctG, qcW, kcW,
                                                     vcTW);
  flash32<<<1024, tb, 0, stream>>>(qcW, kcW, vcTW, small, wdtG, yW);
  gemm_bias_out<<<dim3(16, 64), tb, 0, stream>>>(yW, WtO, small + SM_BO, d_out, 4096, 2048,
                                                 2048, flag);
}